// Round 1
// baseline (298.112 us; speedup 1.0000x reference)
//
#include <hip/hip_runtime.h>
#include <hip/hip_bf16.h>
#include <math.h>

#define NB 2
#define NL 2048
#define ND 1024
#define NH 16
#define NDK 64

typedef __attribute__((ext_vector_type(8))) __bf16 bf16x8;
typedef __attribute__((ext_vector_type(4))) float f32x4;
typedef __attribute__((ext_vector_type(4))) short short4v;

__device__ __forceinline__ short f2bf(float f) {
    union { float f; unsigned u; } v; v.f = f;
    unsigned u = v.u;
    u += 0x7FFF + ((u >> 16) & 1);   // RNE
    return (short)(u >> 16);
}

// ---------------------------------------------------------------------------
// GEMM: C[4096][1024] = A[4096][1024] @ Bw[1024][1024]^T + bias
// ABF16: A is bf16 (short*) if 1, else f32
// EPI: 0 = scatter Q [B,H,L,DK] with 0.125 scale (bf16)
//      1 = scatter K [B,H,L,DK] (bf16)
//      2 = scatter V^T [B,H,DK,L] (bf16)
//      3 = plain f32 [4096][1024] output
// ---------------------------------------------------------------------------
template<int ABF16, int EPI>
__global__ __launch_bounds__(256) void gemm_bt(const void* __restrict__ Ain,
                                               const float* __restrict__ Bw,
                                               const float* __restrict__ bias,
                                               void* __restrict__ out) {
    __shared__ alignas(16) short As[128][40];
    __shared__ alignas(16) short Bs[128][40];

    const int tid  = threadIdx.x;
    const int lane = tid & 63;
    const int w    = tid >> 6;
    const int wr   = w >> 1, wc = w & 1;
    const int lr   = lane >> 4, lc = lane & 15;
    const int m0   = blockIdx.y * 128;
    const int n0   = blockIdx.x * 128;

    f32x4 acc[4][4] = {};

    for (int k0 = 0; k0 < 1024; k0 += 32) {
        // ---- stage A tile [128][32] ----
        if (ABF16) {
            const short* A = (const short*)Ain;
            #pragma unroll
            for (int p = 0; p < 2; ++p) {
                int lin = p * 256 + tid;
                int row = lin >> 2;
                int col = (lin & 3) * 8;
                bf16x8 v = *(const bf16x8*)&A[(m0 + row) * 1024 + k0 + col];
                *(bf16x8*)&As[row][col] = v;
            }
        } else {
            const float* A = (const float*)Ain;
            #pragma unroll
            for (int p = 0; p < 4; ++p) {
                int lin = p * 256 + tid;
                int row = lin >> 3;
                int col = (lin & 7) * 4;
                f32x4 v = *(const f32x4*)&A[(m0 + row) * 1024 + k0 + col];
                short4v sv;
                sv[0] = f2bf(v[0]); sv[1] = f2bf(v[1]);
                sv[2] = f2bf(v[2]); sv[3] = f2bf(v[3]);
                *(short4v*)&As[row][col] = sv;
            }
        }
        // ---- stage B tile [128][32] (weights, always f32) ----
        #pragma unroll
        for (int p = 0; p < 4; ++p) {
            int lin = p * 256 + tid;
            int row = lin >> 3;
            int col = (lin & 7) * 4;
            f32x4 v = *(const f32x4*)&Bw[(n0 + row) * 1024 + k0 + col];
            short4v sv;
            sv[0] = f2bf(v[0]); sv[1] = f2bf(v[1]);
            sv[2] = f2bf(v[2]); sv[3] = f2bf(v[3]);
            *(short4v*)&Bs[row][col] = sv;
        }
        __syncthreads();

        bf16x8 a[4], b[4];
        #pragma unroll
        for (int mt = 0; mt < 4; ++mt)
            a[mt] = *(const bf16x8*)&As[wr * 64 + mt * 16 + lc][lr * 8];
        #pragma unroll
        for (int nt = 0; nt < 4; ++nt)
            b[nt] = *(const bf16x8*)&Bs[wc * 64 + nt * 16 + lc][lr * 8];
        #pragma unroll
        for (int mt = 0; mt < 4; ++mt)
            #pragma unroll
            for (int nt = 0; nt < 4; ++nt)
                acc[mt][nt] = __builtin_amdgcn_mfma_f32_16x16x32_bf16(
                    a[mt], b[nt], acc[mt][nt], 0, 0, 0);
        __syncthreads();
    }

    // ---- epilogue ----
    #pragma unroll
    for (int mt = 0; mt < 4; ++mt) {
        #pragma unroll
        for (int nt = 0; nt < 4; ++nt) {
            #pragma unroll
            for (int r = 0; r < 4; ++r) {
                int grow = m0 + wr * 64 + mt * 16 + lr * 4 + r;
                int gcol = n0 + wc * 64 + nt * 16 + lc;
                float val = acc[mt][nt][r] + bias[gcol];
                if (EPI == 3) {
                    ((float*)out)[grow * 1024 + gcol] = val;
                } else {
                    int b_ = grow >> 11, l_ = grow & 2047;
                    int h_ = gcol >> 6, dk_ = gcol & 63;
                    if (EPI == 0) {
                        ((short*)out)[((b_ * 16 + h_) * 2048 + l_) * 64 + dk_] =
                            f2bf(val * 0.125f);
                    } else if (EPI == 1) {
                        ((short*)out)[((b_ * 16 + h_) * 2048 + l_) * 64 + dk_] =
                            f2bf(val);
                    } else {
                        ((short*)out)[((b_ * 16 + h_) * 64 + dk_) * 2048 + l_] =
                            f2bf(val);
                    }
                }
            }
        }
    }
}

// ---------------------------------------------------------------------------
// Flash attention (causal). Q,K: [B*H][L][64] bf16, Vt: [B*H][64][L] bf16.
// Output AO: [B][L][D] bf16. One wave = 32 q-rows; block = 4 waves = 128 rows.
// ---------------------------------------------------------------------------
__global__ __launch_bounds__(256) void flash_attn(const short* __restrict__ Q,
                                                  const short* __restrict__ K,
                                                  const short* __restrict__ Vt,
                                                  short* __restrict__ AO) {
    __shared__ alignas(16) short Plds[4][32][40];

    const int tid  = threadIdx.x;
    const int lane = tid & 63;
    const int w    = tid >> 6;
    const int lr   = lane >> 4, lc = lane & 15;
    const int bh   = blockIdx.x;          // 0..31
    const int b_   = bh >> 4, h_ = bh & 15;
    const int q0   = blockIdx.y * 128 + w * 32;

    const short* Qh = Q  + bh * (NL * NDK);
    const short* Kh = K  + bh * (NL * NDK);
    const short* Vh = Vt + bh * (NDK * NL);

    // Q fragments (scale already folded in at projection time)
    bf16x8 qf[2][2];
    #pragma unroll
    for (int mt = 0; mt < 2; ++mt)
        #pragma unroll
        for (int ks = 0; ks < 2; ++ks)
            qf[mt][ks] = *(const bf16x8*)&Qh[(q0 + mt * 16 + lc) * 64 + ks * 32 + lr * 8];

    f32x4 o[2][4] = {};
    float m_i[2][4], l_i[2][4];
    #pragma unroll
    for (int mt = 0; mt < 2; ++mt)
        #pragma unroll
        for (int r = 0; r < 4; ++r) { m_i[mt][r] = -INFINITY; l_i[mt][r] = 0.f; }

    const int nb = q0 / 32 + 1;
    for (int kb = 0; kb < nb; ++kb) {
        const int kv0 = kb * 32;

        // S = Q @ K^T  (32 q-rows x 32 kv-cols)
        f32x4 s[2][2] = {};
        #pragma unroll
        for (int ks = 0; ks < 2; ++ks) {
            #pragma unroll
            for (int nt = 0; nt < 2; ++nt) {
                bf16x8 kf = *(const bf16x8*)&Kh[(kv0 + nt * 16 + lc) * 64 + ks * 32 + lr * 8];
                #pragma unroll
                for (int mt = 0; mt < 2; ++mt)
                    s[mt][nt] = __builtin_amdgcn_mfma_f32_16x16x32_bf16(
                        qf[mt][ks], kf, s[mt][nt], 0, 0, 0);
            }
        }

        // causal mask: only the diagonal block is partial (kv0 == q0 there)
        if (kb == nb - 1) {
            #pragma unroll
            for (int mt = 0; mt < 2; ++mt)
                #pragma unroll
                for (int nt = 0; nt < 2; ++nt)
                    #pragma unroll
                    for (int r = 0; r < 4; ++r) {
                        int qq = mt * 16 + lr * 4 + r;
                        int kk = nt * 16 + lc;
                        if (kk > qq) s[mt][nt][r] = -1e30f;
                    }
        }

        // online softmax (rows distributed over 16-lane groups)
        #pragma unroll
        for (int mt = 0; mt < 2; ++mt) {
            #pragma unroll
            for (int r = 0; r < 4; ++r) {
                float mx = fmaxf(s[mt][0][r], s[mt][1][r]);
                #pragma unroll
                for (int off = 1; off < 16; off <<= 1)
                    mx = fmaxf(mx, __shfl_xor(mx, off, 64));
                float mnew  = fmaxf(m_i[mt][r], mx);
                float alpha = __expf(m_i[mt][r] - mnew);
                float p0 = __expf(s[mt][0][r] - mnew);
                float p1 = __expf(s[mt][1][r] - mnew);
                s[mt][0][r] = p0; s[mt][1][r] = p1;
                float rs = p0 + p1;
                #pragma unroll
                for (int off = 1; off < 16; off <<= 1)
                    rs += __shfl_xor(rs, off, 64);
                l_i[mt][r] = l_i[mt][r] * alpha + rs;
                m_i[mt][r] = mnew;
                #pragma unroll
                for (int dt = 0; dt < 4; ++dt) o[mt][dt][r] *= alpha;
            }
        }

        // P -> LDS (S-layout) -> reload as MFMA A-fragments (wave-private)
        #pragma unroll
        for (int mt = 0; mt < 2; ++mt)
            #pragma unroll
            for (int nt = 0; nt < 2; ++nt)
                #pragma unroll
                for (int r = 0; r < 4; ++r)
                    Plds[w][mt * 16 + lr * 4 + r][nt * 16 + lc] = f2bf(s[mt][nt][r]);
        bf16x8 pf[2];
        #pragma unroll
        for (int mt = 0; mt < 2; ++mt)
            pf[mt] = *(const bf16x8*)&Plds[w][mt * 16 + lc][lr * 8];

        // O += P @ V   (V^T layout: contiguous along kv)
        #pragma unroll
        for (int dt = 0; dt < 4; ++dt) {
            bf16x8 vf = *(const bf16x8*)&Vh[(dt * 16 + lc) * NL + kv0 + lr * 8];
            #pragma unroll
            for (int mt = 0; mt < 2; ++mt)
                o[mt][dt] = __builtin_amdgcn_mfma_f32_16x16x32_bf16(
                    pf[mt], vf, o[mt][dt], 0, 0, 0);
        }
    }

    // epilogue: O / l, write [B][L][D] bf16
    #pragma unroll
    for (int mt = 0; mt < 2; ++mt)
        #pragma unroll
        for (int dt = 0; dt < 4; ++dt)
            #pragma unroll
            for (int r = 0; r < 4; ++r) {
                int q = q0 + mt * 16 + lr * 4 + r;
                int d = dt * 16 + lc;
                float val = o[mt][dt][r] / l_i[mt][r];
                AO[(b_ * NL + q) * ND + h_ * 64 + d] = f2bf(val);
            }
}

// ---------------------------------------------------------------------------
extern "C" void kernel_launch(void* const* d_in, const int* in_sizes, int n_in,
                              void* d_out, int out_size, void* d_ws, size_t ws_size,
                              hipStream_t stream) {
    const float* query = (const float*)d_in[0];
    const float* key   = (const float*)d_in[1];
    const float* value = (const float*)d_in[2];
    // d_in[3] = mask: known causal triu(k=1), handled analytically
    const float* Wq = (const float*)d_in[4];
    const float* bq = (const float*)d_in[5];
    const float* Wk = (const float*)d_in[6];
    const float* bk = (const float*)d_in[7];
    const float* Wv = (const float*)d_in[8];
    const float* bv = (const float*)d_in[9];
    const float* Wo = (const float*)d_in[10];
    const float* bo = (const float*)d_in[11];
    float* out = (float*)d_out;

    char* ws = (char*)d_ws;
    short* q_ws  = (short*)(ws);                         // 8 MB  [B,H,L,DK] bf16
    short* k_ws  = (short*)(ws + 8ll * 1024 * 1024);     // 8 MB  [B,H,L,DK] bf16
    short* vt_ws = (short*)(ws + 16ll * 1024 * 1024);    // 8 MB  [B,H,DK,L] bf16
    short* ao_ws = (short*)(ws + 24ll * 1024 * 1024);    // 8 MB  [B,L,D]   bf16

    dim3 blk(256);
    dim3 grd(8, 32);   // N/128, M/128

    gemm_bt<0, 0><<<grd, blk, 0, stream>>>(query, Wq, bq, q_ws);
    gemm_bt<0, 1><<<grd, blk, 0, stream>>>(key,   Wk, bk, k_ws);
    gemm_bt<0, 2><<<grd, blk, 0, stream>>>(value, Wv, bv, vt_ws);

    flash_attn<<<dim3(32, 16), blk, 0, stream>>>(q_ws, k_ws, vt_ws, ao_ws);

    gemm_bt<1, 3><<<grd, blk, 0, stream>>>(ao_ws, Wo, bo, out);
}

// Round 3
// 177.897 us; speedup vs baseline: 1.6758x; 1.6758x over previous
//
#include <hip/hip_runtime.h>
#include <hip/hip_bf16.h>
#include <math.h>

#define NL 2048
#define ND 1024

typedef __attribute__((ext_vector_type(8))) __bf16 bf16x8;
typedef __attribute__((ext_vector_type(4))) float f32x4;
typedef __attribute__((ext_vector_type(16))) float f32x16;
typedef __attribute__((ext_vector_type(4))) short short4v;
typedef __attribute__((ext_vector_type(2))) unsigned uint2v;
typedef __attribute__((ext_vector_type(4))) unsigned uint4v;

__device__ __forceinline__ short f2bf(float f) {
    union { float f; unsigned u; } v; v.f = f;
    unsigned u = v.u;
    u += 0x7FFF + ((u >> 16) & 1);   // RNE
    return (short)(u >> 16);
}

__device__ __forceinline__ unsigned cvtpk2(float lo, float hi) {
    unsigned r;
    asm("v_cvt_pk_bf16_f32 %0, %1, %2" : "=v"(r) : "v"(lo), "v"(hi));
    return r;
}

__device__ __forceinline__ void gload16(const short* g, short* l) {
    __builtin_amdgcn_global_load_lds(
        (const __attribute__((address_space(1))) void*)g,
        (__attribute__((address_space(3))) void*)l, 16, 0, 0);
}

// ---------------------------------------------------------------------------
// f32 -> bf16 convert, 3 tensors of `per` elems each (blockIdx.y selects)
// ---------------------------------------------------------------------------
__global__ __launch_bounds__(256) void cvt_f32_bf16_3(const float* __restrict__ a,
                                                      const float* __restrict__ b,
                                                      const float* __restrict__ c,
                                                      short* __restrict__ dst, int per) {
    const float* src = blockIdx.y == 0 ? a : blockIdx.y == 1 ? b : c;
    short* d = dst + (size_t)blockIdx.y * per;
    int i = (blockIdx.x * 256 + threadIdx.x) * 8;
    if (i < per) {
        f32x4 v0 = *(const f32x4*)&src[i];
        f32x4 v1 = *(const f32x4*)&src[i + 4];
        uint4v u = { cvtpk2(v0[0], v0[1]), cvtpk2(v0[2], v0[3]),
                     cvtpk2(v1[0], v1[1]), cvtpk2(v1[2], v1[3]) };
        *(uint4v*)&d[i] = u;
    }
}

// ---------------------------------------------------------------------------
// Fused QKV projection GEMM. C[4096][1024] = X @ W^T + bias, per z in {Q,K,V}.
// A (X): f32, converted during staging. B (W): bf16, global_load_lds.
// Epilogue scatters: z=0 Q*[0.125*log2e] -> [BH][L][64]; z=1 K -> [BH][L][64];
// z=2 V^T -> [BH][64][L].
// ---------------------------------------------------------------------------
__global__ __launch_bounds__(256) void gemm_qkv(
    const float* __restrict__ Xq, const float* __restrict__ Xk, const float* __restrict__ Xv,
    const short* __restrict__ Wqb, const short* __restrict__ Wkb, const short* __restrict__ Wvb,
    const float* __restrict__ bq, const float* __restrict__ bk, const float* __restrict__ bv,
    short* __restrict__ oq, short* __restrict__ ok, short* __restrict__ ov) {
    __shared__ alignas(16) short As[128 * 32];
    __shared__ alignas(16) short Bs[128 * 32];

    const int z = blockIdx.z;
    const float* X  = z == 0 ? Xq : z == 1 ? Xk : Xv;
    const short* Wb = z == 0 ? Wqb : z == 1 ? Wkb : Wvb;
    const float* bi = z == 0 ? bq : z == 1 ? bk : bv;
    short* outp     = z == 0 ? oq : z == 1 ? ok : ov;
    const float scl = z == 0 ? 0.125f * 1.44269504088896f : 1.0f;

    const int tid = threadIdx.x, lane = tid & 63, w = tid >> 6;
    const int wr = w >> 1, wc = w & 1, lr = lane >> 4, lc = lane & 15;
    const int m0 = blockIdx.y * 128, n0 = blockIdx.x * 128;

    const short* gB = &Wb[(n0 + w * 16 + (lane >> 2)) * 1024 + (lane & 3) * 8];
    short* lB0 = &Bs[w * 512];
    short* lB1 = &Bs[w * 512 + 2048];

    f32x4 acc[4][4] = {};

    for (int k0 = 0; k0 < 1024; k0 += 32) {
        gload16(gB + k0, lB0);
        gload16(gB + 64 * 1024 + k0, lB1);
        #pragma unroll
        for (int p = 0; p < 4; ++p) {
            int lin = p * 256 + tid;
            int row = lin >> 3;
            int col = (lin & 7) * 4;
            f32x4 v = *(const f32x4*)&X[(m0 + row) * 1024 + k0 + col];
            uint2v uu = { cvtpk2(v[0], v[1]), cvtpk2(v[2], v[3]) };
            *(uint2v*)&As[row * 32 + col] = uu;
        }
        __syncthreads();

        bf16x8 a[4], b[4];
        #pragma unroll
        for (int mt = 0; mt < 4; ++mt)
            a[mt] = *(const bf16x8*)&As[(wr * 64 + mt * 16 + lc) * 32 + lr * 8];
        #pragma unroll
        for (int nt = 0; nt < 4; ++nt)
            b[nt] = *(const bf16x8*)&Bs[(wc * 64 + nt * 16 + lc) * 32 + lr * 8];
        #pragma unroll
        for (int mt = 0; mt < 4; ++mt)
            #pragma unroll
            for (int nt = 0; nt < 4; ++nt)
                acc[mt][nt] = __builtin_amdgcn_mfma_f32_16x16x32_bf16(
                    a[mt], b[nt], acc[mt][nt], 0, 0, 0);
        __syncthreads();
    }

    #pragma unroll
    for (int mt = 0; mt < 4; ++mt)
        #pragma unroll
        for (int nt = 0; nt < 4; ++nt)
            #pragma unroll
            for (int r = 0; r < 4; ++r) {
                int grow = m0 + wr * 64 + mt * 16 + lr * 4 + r;
                int gcol = n0 + wc * 64 + nt * 16 + lc;
                float val = (acc[mt][nt][r] + bi[gcol]) * scl;
                int b_ = grow >> 11, l_ = grow & 2047;
                int h_ = gcol >> 6, dk_ = gcol & 63;
                if (z == 2)
                    outp[((b_ * 16 + h_) * 64 + dk_) * 2048 + l_] = f2bf(val);
                else
                    outp[((b_ * 16 + h_) * 2048 + l_) * 64 + dk_] = f2bf(val);
            }
}

// ---------------------------------------------------------------------------
// Output projection GEMM: out[4096][1024] f32 = AO(bf16) @ Wo^T(bf16) + bo.
// Both operands staged via global_load_lds.
// ---------------------------------------------------------------------------
__global__ __launch_bounds__(256) void gemm_out(const short* __restrict__ Abf,
                                                const short* __restrict__ Wob,
                                                const float* __restrict__ bo,
                                                float* __restrict__ out) {
    __shared__ alignas(16) short As[128 * 32];
    __shared__ alignas(16) short Bs[128 * 32];

    const int tid = threadIdx.x, lane = tid & 63, w = tid >> 6;
    const int wr = w >> 1, wc = w & 1, lr = lane >> 4, lc = lane & 15;
    const int m0 = blockIdx.y * 128, n0 = blockIdx.x * 128;

    const short* gA = &Abf[(m0 + w * 16 + (lane >> 2)) * 1024 + (lane & 3) * 8];
    const short* gB = &Wob[(n0 + w * 16 + (lane >> 2)) * 1024 + (lane & 3) * 8];
    short* lA0 = &As[w * 512];
    short* lA1 = &As[w * 512 + 2048];
    short* lB0 = &Bs[w * 512];
    short* lB1 = &Bs[w * 512 + 2048];

    f32x4 acc[4][4] = {};

    for (int k0 = 0; k0 < 1024; k0 += 32) {
        gload16(gA + k0, lA0);
        gload16(gA + 64 * 1024 + k0, lA1);
        gload16(gB + k0, lB0);
        gload16(gB + 64 * 1024 + k0, lB1);
        __syncthreads();

        bf16x8 a[4], b[4];
        #pragma unroll
        for (int mt = 0; mt < 4; ++mt)
            a[mt] = *(const bf16x8*)&As[(wr * 64 + mt * 16 + lc) * 32 + lr * 8];
        #pragma unroll
        for (int nt = 0; nt < 4; ++nt)
            b[nt] = *(const bf16x8*)&Bs[(wc * 64 + nt * 16 + lc) * 32 + lr * 8];
        #pragma unroll
        for (int mt = 0; mt < 4; ++mt)
            #pragma unroll
            for (int nt = 0; nt < 4; ++nt)
                acc[mt][nt] = __builtin_amdgcn_mfma_f32_16x16x32_bf16(
                    a[mt], b[nt], acc[mt][nt], 0, 0, 0);
        __syncthreads();
    }

    #pragma unroll
    for (int mt = 0; mt < 4; ++mt)
        #pragma unroll
        for (int nt = 0; nt < 4; ++nt)
            #pragma unroll
            for (int r = 0; r < 4; ++r) {
                int grow = m0 + wr * 64 + mt * 16 + lr * 4 + r;
                int gcol = n0 + wc * 64 + nt * 16 + lc;
                out[grow * 1024 + gcol] = acc[mt][nt][r] + bo[gcol];
            }
}

// ---------------------------------------------------------------------------
// Flash attention, swapped-operand 32x32 structure. No LDS.
// Q,K: [BH][L][64] bf16 (Q pre-scaled by 0.125*log2e), Vt: [BH][64][L] bf16.
// One warp = 32 q-rows. NOTE (round-2 bug fix): in the 32x32 C/D layout each
// lane holds only HALF its q-row's kv scores (rows ...+4*hi); the partner lane
// (lane^32) holds the other half. The online-softmax max/sum must therefore be
// combined across the partner pair with one __shfl_xor(...,32) each, so that
// both halves normalize P with the SAME m and l (guide m214: "31 fmax + 1
// permlane32_swap").
// ---------------------------------------------------------------------------
__global__ __launch_bounds__(256) void flash_attn(const short* __restrict__ Q,
                                                  const short* __restrict__ K,
                                                  const short* __restrict__ Vt,
                                                  short* __restrict__ AO) {
    const int tid  = threadIdx.x;
    const int lane = tid & 63;
    const int w    = tid >> 6;
    const int ql   = lane & 31;
    const int hi   = lane >> 5;
    const int hi8  = hi * 8;

    // XCD-grouped bh, work-balanced tile map
    const int bid  = blockIdx.x;
    const int xcd  = bid & 7;
    const int rest = bid >> 3;
    const int bh   = xcd * 4 + (rest & 3);
    const int y    = rest >> 2;                            // 0..15
    const int t    = (w < 2) ? (2 * y + w) : (63 - 2 * y - (w - 2));
    const int q0   = t * 32;
    const int qa   = q0 + ql;

    const short* Qh = Q  + (size_t)bh * NL * 64;
    const short* Kh = K  + (size_t)bh * NL * 64;
    const short* Vh = Vt + (size_t)bh * 64 * NL;

    bf16x8 qf[4];
    #pragma unroll
    for (int ks = 0; ks < 4; ++ks)
        qf[ks] = *(const bf16x8*)&Qh[(q0 + ql) * 64 + ks * 16 + hi8];

    f32x16 ot0 = {}, ot1 = {};
    float m_i = -3.0e38f, l_i = 0.f;

    const int nkb = (q0 + 95) >> 6;
    for (int kb = 0; kb < nkb; ++kb) {
        const int kv0 = kb * 64;

        // S^T = K @ Q^T  (two 32x32 blocks over kv)
        f32x16 st0 = {}, st1 = {};
        #pragma unroll
        for (int ks = 0; ks < 4; ++ks) {
            bf16x8 kf0 = *(const bf16x8*)&Kh[(kv0 + ql) * 64 + ks * 16 + hi8];
            bf16x8 kf1 = *(const bf16x8*)&Kh[(kv0 + 32 + ql) * 64 + ks * 16 + hi8];
            st0 = __builtin_amdgcn_mfma_f32_32x32x16_bf16(kf0, qf[ks], st0, 0, 0, 0);
            st1 = __builtin_amdgcn_mfma_f32_32x32x16_bf16(kf1, qf[ks], st1, 0, 0, 0);
        }

        // causal mask (only the last kv block can cross the diagonal)
        if (kb == nkb - 1) {
            #pragma unroll
            for (int r = 0; r < 16; ++r) {
                const int cr = (r & 3) + 8 * (r >> 2) + 4 * hi;
                if (kv0 + cr > qa)      st0[r] = -3.0e38f;
                if (kv0 + 32 + cr > qa) st1[r] = -3.0e38f;
            }
        }

        // online softmax (exp2 domain): per-lane partial over its 32 values,
        // then combine with partner lane (lane^32) which holds the other half
        float mx[8];
        #pragma unroll
        for (int i = 0; i < 8; ++i)
            mx[i] = fmaxf(fmaxf(st0[i], st0[i + 8]), fmaxf(st1[i], st1[i + 8]));
        #pragma unroll
        for (int s = 4; s > 0; s >>= 1)
            #pragma unroll
            for (int i = 0; i < s; ++i) mx[i] = fmaxf(mx[i], mx[i + s]);
        float mrow = fmaxf(mx[0], __shfl_xor(mx[0], 32));   // full-row max
        const float mnew  = fmaxf(m_i, mrow);
        const float alpha = exp2f(m_i - mnew);
        float sm[16];
        #pragma unroll
        for (int r = 0; r < 16; ++r) {
            float p0 = exp2f(st0[r] - mnew);
            float p1 = exp2f(st1[r] - mnew);
            st0[r] = p0; st1[r] = p1;
            sm[r] = p0 + p1;
        }
        #pragma unroll
        for (int s = 8; s > 0; s >>= 1)
            #pragma unroll
            for (int i = 0; i < s; ++i) sm[i] += sm[i + s];
        float rowsum = sm[0] + __shfl_xor(sm[0], 32);       // full-row sum
        l_i = l_i * alpha + rowsum;
        m_i = mnew;
        #pragma unroll
        for (int r = 0; r < 16; ++r) { ot0[r] *= alpha; ot1[r] *= alpha; }

        // P (f32, C/D layout) -> bf16 B-fragments via cvt_pk + permlane32_swap
        bf16x8 pf[4];
        #pragma unroll
        for (int blk = 0; blk < 2; ++blk) {
            const f32x16 s = blk ? st1 : st0;
            #pragma unroll
            for (int pks = 0; pks < 2; ++pks) {
                const int b = pks * 8;
                unsigned xa = cvtpk2(s[b + 0], s[b + 1]);
                unsigned xb = cvtpk2(s[b + 2], s[b + 3]);
                unsigned ya = cvtpk2(s[b + 4], s[b + 5]);
                unsigned yb = cvtpk2(s[b + 6], s[b + 7]);
                uint2v s0 = __builtin_amdgcn_permlane32_swap(xa, ya, false, false);
                uint2v s1 = __builtin_amdgcn_permlane32_swap(xb, yb, false, false);
                union { unsigned u[4]; bf16x8 v; } pu;
                pu.u[0] = s0[0]; pu.u[1] = s1[0]; pu.u[2] = s0[1]; pu.u[3] = s1[1];
                pf[blk * 2 + pks] = pu.v;
            }
        }

        // O^T += V^T @ P^T   (two 32-dk blocks)
        #pragma unroll
        for (int ks = 0; ks < 4; ++ks) {
            bf16x8 vf0 = *(const bf16x8*)&Vh[ql * NL + kv0 + ks * 16 + hi8];
            bf16x8 vf1 = *(const bf16x8*)&Vh[(32 + ql) * NL + kv0 + ks * 16 + hi8];
            ot0 = __builtin_amdgcn_mfma_f32_32x32x16_bf16(vf0, pf[ks], ot0, 0, 0, 0);
            ot1 = __builtin_amdgcn_mfma_f32_32x32x16_bf16(vf1, pf[ks], ot1, 0, 0, 0);
        }
    }

    // epilogue: O = O^T / l, write [B][L][D] bf16 (l now row-uniform)
    const int b_ = bh >> 4, h_ = bh & 15;
    const float inv = 1.f / l_i;
    short* aoRow = AO + ((size_t)(b_ * NL + qa)) * ND + h_ * 64;
    #pragma unroll
    for (int db = 0; db < 2; ++db) {
        const f32x16 o = db ? ot1 : ot0;
        #pragma unroll
        for (int g = 0; g < 4; ++g) {
            short4v sv;
            #pragma unroll
            for (int i = 0; i < 4; ++i) sv[i] = f2bf(o[g * 4 + i] * inv);
            *(short4v*)&aoRow[db * 32 + g * 8 + 4 * hi] = sv;
        }
    }
}

// ---------------------------------------------------------------------------
extern "C" void kernel_launch(void* const* d_in, const int* in_sizes, int n_in,
                              void* d_out, int out_size, void* d_ws, size_t ws_size,
                              hipStream_t stream) {
    const float* query = (const float*)d_in[0];
    const float* key   = (const float*)d_in[1];
    const float* value = (const float*)d_in[2];
    // d_in[3] = mask: known causal triu(k=1), handled analytically
    const float* Wq = (const float*)d_in[4];
    const float* bq = (const float*)d_in[5];
    const float* Wk = (const float*)d_in[6];
    const float* bk = (const float*)d_in[7];
    const float* Wv = (const float*)d_in[8];
    const float* bv = (const float*)d_in[9];
    const float* Wo = (const float*)d_in[10];
    const float* bo = (const float*)d_in[11];

    short* ws    = (short*)d_ws;
    short* q_ws  = ws;                       // [0,4M) shorts
    short* k_ws  = ws + (4 << 20);           // [4M,8M)
    short* vt_ws = ws + (8 << 20);           // [8M,12M)
    short* wbf   = ws + (12 << 20);          // [12M,15M): Wq,Wk,Wv bf16 (dead after gemm_qkv)
    short* ao_ws = ws + (12 << 20);          // [12M,16M): AO bf16 (written by flash)
    short* wobf  = ws;                       // [0,1M): Wo bf16 (q_ws dead after flash)

    // 1. convert Wq/Wk/Wv to bf16
    cvt_f32_bf16_3<<<dim3(512, 3), 256, 0, stream>>>(Wq, Wk, Wv, wbf, 1 << 20);
    // 2. fused QKV projections (768 blocks = 3/CU)
    gemm_qkv<<<dim3(8, 32, 3), 256, 0, stream>>>(
        query, key, value,
        wbf, wbf + (1 << 20), wbf + (2 << 20),
        bq, bk, bv, q_ws, k_ws, vt_ws);
    // 3. causal flash attention
    flash_attn<<<dim3(512), 256, 0, stream>>>(q_ws, k_ws, vt_ws, ao_ws);
    // 4. convert Wo to bf16 (into dead q_ws space)
    cvt_f32_bf16_3<<<dim3(512, 1), 256, 0, stream>>>(Wo, Wo, Wo, wobf, 1 << 20);
    // 5. output projection
    gemm_out<<<dim3(8, 32), 256, 0, stream>>>(ao_ws, wobf, bo, (float*)d_out);
}